// Round 8
// baseline (269.899 us; speedup 1.0000x reference)
//
#include <hip/hip_runtime.h>

// QattenNet: B=E*T=8192, S=256, A=32, O=128, QH1=128, QD=64, C1=128, H=4.
// R11: R10's top-5 exposed the real system structure: 2x512MB harness poison
// fills run HBM-saturated (~156us/iter, fixed) and their ~256MB cache-dirty
// tail drains DURING our kernel -> our fs stream is contention-limited to
// ~1-1.7 TB/s no matter the kernel shape (R3..R10 all ~75-90us main).
// Controllable slice = prep(1) + main(78) + final(4.4). This round:
//  - Single fused kernel: stream fs -> g in LDS (each wave later consumes
//    exactly the rows it produced), MLP phases (R9's verified NB=8 tiles),
//    v in registers, fused epilogue (R6's verified reduction) -> out.
//    Deletes qatten_final dispatch + 16MB g/v workspace round-trip.
//  - Stream-first: all 1024 blocks resident; every wave's 16-deep fs batch
//    issues at t=0 (max read share vs fill drain); MLP hides under the tail.
//  - launch_bounds(256,5): 102 VGPR cap (stream needs ~84 live), LDS 20.5KB.

static constexpr int Sd  = 256;
static constexpr int Ad  = 32;
static constexpr int Od  = 128;
static constexpr int QDd = 64;
static constexpr int NB  = 8;
static constexpr int NBLK = 1024;       // 8192 / NB

__global__ void qatten_prep(const float* __restrict__ Wk, const float* __restrict__ bk,
                            float* __restrict__ WkT, float* __restrict__ bkSum)
{
    int idx = blockIdx.x * 256 + threadIdx.x;   // 0..8191
    int k = idx >> 7;          // 0..63
    int o = idx & 127;         // 0..127
    float s = 0.f;
#pragma unroll
    for (int h = 0; h < 4; ++h) s += Wk[h * (Od * QDd) + o * QDd + k];
    WkT[k * Od + o] = s;
    if (idx < QDd) {
        float t = 0.f;
#pragma unroll
        for (int h = 0; h < 4; ++h) t += bk[h * QDd + idx];
        bkSum[idx] = t;
    }
}

union SEmb {
    float s[NB][Sd];        // 8 KB, live until end of phase 2
    float emb[NB][68];      // 2.125 KB, live phases 3+
};

__global__ __launch_bounds__(256, 5) void qatten_fused(
    const float* __restrict__ qv, const float* __restrict__ st, const float* __restrict__ fs,
    const float* __restrict__ Wq1, const float* __restrict__ bq1,
    const float* __restrict__ Wq2, const float* __restrict__ bq2,
    const float* __restrict__ Wc1, const float* __restrict__ bc1,
    const float* __restrict__ Wc2, const float* __restrict__ bc2,
    const float* __restrict__ WkT, const float* __restrict__ bkSum,
    float* __restrict__ out)
{
    __shared__ SEmb u;                  // 8 KB
    __shared__ float h_lds[NB][260];    // 8.125 KB (cols 0-127: h1, 128-255: hc)
    __shared__ float g_lds[NB][128];    // 4 KB     total 20.5 KB

    const int tid = threadIdx.x;
    const int b0 = blockIdx.x * NB;

    // ---- stream phase FIRST: g[row] = sum_a q[row,a]*f[row,a,:] -> g_lds ----
    // wave w owns rows 2w, 2w+1; 16 float4 loads issued into static register
    // arrays before consumption (2 batches of 8 chunks x 2 rows). lane l owns
    // float4 slot (l&31); chunk ii covers agent a = 2*ii + (l>>5).
    {
        const int w = tid >> 6;
        const int l = tid & 63;
        const int r0 = b0 + 2 * w;
        const float4* __restrict__ f0 = (const float4*)fs + (size_t)r0 * (Ad * Od / 4);
        const float4* __restrict__ f1 = f0 + (Ad * Od / 4);
        const float q0 = qv[(size_t)r0 * Ad + (l & 31)];
        const float q1 = qv[(size_t)(r0 + 1) * Ad + (l & 31)];
        float4 a0 = {0.f, 0.f, 0.f, 0.f}, a1 = {0.f, 0.f, 0.f, 0.f};
#pragma unroll
        for (int batch = 0; batch < 2; ++batch) {
            float4 x0[8], x1[8];
#pragma unroll
            for (int i = 0; i < 8; ++i) {
                x0[i] = f0[(batch * 8 + i) * 64 + l];
                x1[i] = f1[(batch * 8 + i) * 64 + l];
            }
#pragma unroll
            for (int i = 0; i < 8; ++i) {
                const int ii = batch * 8 + i;
                const float qa0 = __shfl(q0, 2 * ii + (l >> 5), 64);
                const float qa1 = __shfl(q1, 2 * ii + (l >> 5), 64);
                a0.x = fmaf(qa0, x0[i].x, a0.x);
                a0.y = fmaf(qa0, x0[i].y, a0.y);
                a0.z = fmaf(qa0, x0[i].z, a0.z);
                a0.w = fmaf(qa0, x0[i].w, a0.w);
                a1.x = fmaf(qa1, x1[i].x, a1.x);
                a1.y = fmaf(qa1, x1[i].y, a1.y);
                a1.z = fmaf(qa1, x1[i].z, a1.z);
                a1.w = fmaf(qa1, x1[i].w, a1.w);
            }
        }
        // combine the two half-wave partials (a-parity split)
        a0.x += __shfl_xor(a0.x, 32, 64);
        a0.y += __shfl_xor(a0.y, 32, 64);
        a0.z += __shfl_xor(a0.z, 32, 64);
        a0.w += __shfl_xor(a0.w, 32, 64);
        a1.x += __shfl_xor(a1.x, 32, 64);
        a1.y += __shfl_xor(a1.y, 32, 64);
        a1.z += __shfl_xor(a1.z, 32, 64);
        a1.w += __shfl_xor(a1.w, 32, 64);
        if (l < 32) {
            *(float4*)&g_lds[2 * w][l * 4]     = a0;
            *(float4*)&g_lds[2 * w + 1][l * 4] = a1;
        }
        // note: each wave reads back exactly the g rows it wrote (row = tid>>5
        // in the epilogue maps wave w -> rows 2w,2w+1), and __syncthreads
        // barriers intervene anyway.
    }

    // ---- stage s (8x256): 2 float4 per thread, coalesced ----
    {
        const float4* sp = (const float4*)(st + (size_t)b0 * Sd);
        float4* sl = (float4*)&u.s[0][0];
        sl[tid]       = sp[tid];
        sl[tid + 256] = sp[tid + 256];
    }
    __syncthreads();

    // ---- phase 2: h = relu(s @ [Wq1|Wc1] + [bq1|bc1]); 2 rows x 4 cols ----
    {
        const int wg = tid & 63;                 // col group: cols 4wg..4wg+3
        const int rg = (tid >> 6) << 1;          // rows rg, rg+1 (wave-uniform)
        const float* __restrict__ Wb = (wg < 32) ? (Wq1 + 4 * wg)
                                                 : (Wc1 + 4 * (wg - 32));
        const float4 bb4 = (wg < 32) ? *(const float4*)&bq1[4 * wg]
                                     : *(const float4*)&bc1[4 * (wg - 32)];
        float acc[2][4];
#pragma unroll
        for (int r = 0; r < 2; ++r)
#pragma unroll
            for (int c = 0; c < 4; ++c) acc[r][c] = 0.f;

        for (int k = 0; k < Sd; k += 4) {
            float w[4][4];
#pragma unroll
            for (int kk = 0; kk < 4; ++kk) {
                const float4 t = *(const float4*)&Wb[(size_t)(k + kk) * 128];
                w[kk][0] = t.x; w[kk][1] = t.y; w[kk][2] = t.z; w[kk][3] = t.w;
            }
#pragma unroll
            for (int r = 0; r < 2; ++r) {
                const float4 s4 = *(const float4*)&u.s[rg + r][k];
                float a0 = acc[r][0], a1 = acc[r][1], a2 = acc[r][2], a3 = acc[r][3];
                a0 = fmaf(s4.x, w[0][0], a0); a1 = fmaf(s4.x, w[0][1], a1);
                a2 = fmaf(s4.x, w[0][2], a2); a3 = fmaf(s4.x, w[0][3], a3);
                a0 = fmaf(s4.y, w[1][0], a0); a1 = fmaf(s4.y, w[1][1], a1);
                a2 = fmaf(s4.y, w[1][2], a2); a3 = fmaf(s4.y, w[1][3], a3);
                a0 = fmaf(s4.z, w[2][0], a0); a1 = fmaf(s4.z, w[2][1], a1);
                a2 = fmaf(s4.z, w[2][2], a2); a3 = fmaf(s4.z, w[2][3], a3);
                a0 = fmaf(s4.w, w[3][0], a0); a1 = fmaf(s4.w, w[3][1], a1);
                a2 = fmaf(s4.w, w[3][2], a2); a3 = fmaf(s4.w, w[3][3], a3);
                acc[r][0] = a0; acc[r][1] = a1; acc[r][2] = a2; acc[r][3] = a3;
            }
        }
#pragma unroll
        for (int r = 0; r < 2; ++r) {
            float4 o;
            o.x = fmaxf(acc[r][0] + bb4.x, 0.f);
            o.y = fmaxf(acc[r][1] + bb4.y, 0.f);
            o.z = fmaxf(acc[r][2] + bb4.z, 0.f);
            o.w = fmaxf(acc[r][3] + bb4.w, 0.f);
            *(float4*)&h_lds[rg + r][4 * wg] = o;
        }
    }
    __syncthreads();   // h ready; u.s dead -> u.emb may be written

    // ---- phase 3: emb = h1 @ Wq2 + bq2; thread = 1 row x 2 cols ----
    {
        const int c2  = tid & 31;       // cols 2c2, 2c2+1 (of 64)
        const int row = tid >> 5;       // 0..7
        float a0 = 0.f, a1 = 0.f;
        for (int k = 0; k < 128; k += 4) {
            float2 w[4];
#pragma unroll
            for (int kk = 0; kk < 4; ++kk)
                w[kk] = *(const float2*)&Wq2[(size_t)(k + kk) * 64 + 2 * c2];
            const float4 h4 = *(const float4*)&h_lds[row][k];
            a0 = fmaf(h4.x, w[0].x, a0);  a1 = fmaf(h4.x, w[0].y, a1);
            a0 = fmaf(h4.y, w[1].x, a0);  a1 = fmaf(h4.y, w[1].y, a1);
            a0 = fmaf(h4.z, w[2].x, a0);  a1 = fmaf(h4.z, w[2].y, a1);
            a0 = fmaf(h4.w, w[3].x, a0);  a1 = fmaf(h4.w, w[3].y, a1);
        }
        const float2 b2 = *(const float2*)&bq2[2 * c2];
        float2 o; o.x = a0 + b2.x; o.y = a1 + b2.y;
        *(float2*)&u.emb[row][2 * c2] = o;
    }
    __syncthreads();   // emb ready

    // ---- phase 4 + fused epilogue: v in regs, dot with g_lds, bias, out ----
    // thread = 1 row x 4 cols of v; 32 lanes per row reduce everything.
    {
        const int cg  = tid & 31;       // v cols 4cg..4cg+3 (of 128)
        const int row = tid >> 5;       // 0..7
        const int b   = b0 + row;

        float acc[4] = {0.f, 0.f, 0.f, 0.f};
        for (int k = 0; k < QDd; k += 4) {
            float w[4][4];
#pragma unroll
            for (int kk = 0; kk < 4; ++kk) {
                const float4 t = *(const float4*)&WkT[(size_t)(k + kk) * 128 + 4 * cg];
                w[kk][0] = t.x; w[kk][1] = t.y; w[kk][2] = t.z; w[kk][3] = t.w;
            }
            const float4 e4 = *(const float4*)&u.emb[row][k];
#pragma unroll
            for (int c = 0; c < 4; ++c) {
                float a = acc[c];
                a = fmaf(e4.x, w[0][c], a);
                a = fmaf(e4.y, w[1][c], a);
                a = fmaf(e4.z, w[2][c], a);
                a = fmaf(e4.w, w[3][c], a);
                acc[c] = a;
            }
        }
        // d = partial of g[b]·v[b]
        const float4 g4 = *(const float4*)&g_lds[row][4 * cg];
        float d = acc[0] * g4.x;
        d = fmaf(acc[1], g4.y, d);
        d = fmaf(acc[2], g4.z, d);
        d = fmaf(acc[3], g4.w, d);
        // bias partials: beta = emb·bkSum, c = hc·Wc2, sumq = sum(q[b,:])
        float pb = fmaf(u.emb[row][cg],      bkSum[cg],      0.f);
        pb       = fmaf(u.emb[row][cg + 32], bkSum[cg + 32], pb);
        float pc = 0.f;
#pragma unroll
        for (int j = 0; j < 4; ++j)
            pc = fmaf(h_lds[row][128 + cg + 32 * j], Wc2[cg + 32 * j], pc);
        float pq = qv[(size_t)b * Ad + cg];
#pragma unroll
        for (int dd = 16; dd >= 1; dd >>= 1) {
            d  += __shfl_down(d,  dd, 32);
            pb += __shfl_down(pb, dd, 32);
            pc += __shfl_down(pc, dd, 32);
            pq += __shfl_down(pq, dd, 32);
        }
        if (cg == 0)
            out[b] = d + (pc + bc2[0]) + pb * pq;
    }
}

extern "C" void kernel_launch(void* const* d_in, const int* in_sizes, int n_in,
                              void* d_out, int out_size, void* d_ws, size_t ws_size,
                              hipStream_t stream) {
    const float* qv  = (const float*)d_in[0];
    const float* st  = (const float*)d_in[1];
    const float* fs  = (const float*)d_in[2];
    const float* Wq1 = (const float*)d_in[3];
    const float* bq1 = (const float*)d_in[4];
    const float* Wq2 = (const float*)d_in[5];
    const float* bq2 = (const float*)d_in[6];
    const float* Wk  = (const float*)d_in[7];
    const float* bk  = (const float*)d_in[8];
    const float* Wc1 = (const float*)d_in[9];
    const float* bc1 = (const float*)d_in[10];
    const float* Wc2 = (const float*)d_in[11];
    const float* bc2 = (const float*)d_in[12];
    float* out = (float*)d_out;

    // workspace (floats): WkT 8192 | bkSum 64   (33 KB)
    float* WkT   = (float*)d_ws;
    float* bkSum = WkT + QDd * Od;          // +8192

    qatten_prep<<<32, 256, 0, stream>>>(Wk, bk, WkT, bkSum);
    qatten_fused<<<NBLK, 256, 0, stream>>>(qv, st, fs, Wq1, bq1, Wq2, bq2,
                                           Wc1, bc1, Wc2, bc2, WkT, bkSum, out);
}